// Round 5
// baseline (12.541 us; speedup 1.0000x reference)
//
#include <hip/hip_runtime.h>

#define NB 4096
#define TPB 1024
#define WPB 16                    // waves per block
#define BPB 8                     // bodies per block (2 waves per body)
#define NBLK (NB / BPB)           // 512 blocks -> 2 per CU, 8 waves/SIMD
#define NPAIR (NB / 2)            // 2048 packed source-pairs
#define HALF (NPAIR / 2)          // 1024 pairs per half
#define NT (HALF / 64)            // 16 inner iterations per wave

// Two waves per body k (halves h=0/1 of the source range). Sources packed in
// LDS as (qx0,qy0,qx1,qy1) float4 + (m0,m1) float2. Self-pair handled by a
// 1e-20 bias on sq (dx=dy=0 -> contribution exactly 0, no NaN, no clamp op).
// Per-wave butterfly reduce, then the two half-sums combine via LDS in fixed
// order -> bitwise deterministic.
__global__ __launch_bounds__(TPB) void nbody_wave2(
    const float* __restrict__ x, const float* __restrict__ m,
    float4* __restrict__ out)
{
    __shared__ float4 qp[NPAIR];  // 32 KB
    __shared__ float2 mp[NPAIR];  // 16 KB
    __shared__ float2 red[WPB];

    const int tid = threadIdx.x;

    #pragma unroll
    for (int t = 0; t < NPAIR / TPB; ++t) {   // 2 iters
        const int j = t * TPB + tid;
        const float4 a = ((const float4*)x)[2 * j];
        const float4 b = ((const float4*)x)[2 * j + 1];
        qp[j] = make_float4(a.x, a.y, b.x, b.y);
        mp[j] = ((const float2*)m)[j];
    }
    __syncthreads();

    const int wave = tid >> 6;
    const int lane = tid & 63;
    const int b    = wave >> 1;               // body slot in block
    const int h    = wave & 1;                // source half
    const int k    = blockIdx.x * BPB + b;

    const float4 xk = ((const float4*)x)[k];  // wave-uniform -> scalar load
    const float qx = xk.x, qy = xk.y;
    float ax = 0.f, ay = 0.f;

    const int base = h * HALF;
    #pragma unroll 8
    for (int t = 0; t < NT; ++t) {
        const int p = base + t * 64 + lane;
        const float4 q = qp[p];
        const float2 mm = mp[p];
        {
            const float dx = qx - q.x;
            const float dy = qy - q.y;
            const float sq = fmaf(dx, dx, fmaf(dy, dy, 1e-20f));
            const float r = __builtin_amdgcn_rsqf(sq);
            const float w = r * r * r * mm.x;
            ax = fmaf(dx, w, ax);
            ay = fmaf(dy, w, ay);
        }
        {
            const float dx = qx - q.z;
            const float dy = qy - q.w;
            const float sq = fmaf(dx, dx, fmaf(dy, dy, 1e-20f));
            const float r = __builtin_amdgcn_rsqf(sq);
            const float w = r * r * r * mm.y;
            ax = fmaf(dx, w, ax);
            ay = fmaf(dy, w, ay);
        }
    }

    // Adjacent pairs |k-i|==1 carry weight 2 under tril(.,diagonal=1); main
    // loop counted them once. Half-0 wave, lanes 0/1, add the extra unit.
    if (h == 0) {
        int nbi = -1;
        if (lane == 0 && k > 0) nbi = k - 1;
        else if (lane == 1 && k < NB - 1) nbi = k + 1;
        if (nbi >= 0) {
            const float4 q = qp[nbi >> 1];
            const float2 mm = mp[nbi >> 1];
            const float sx = (nbi & 1) ? q.z : q.x;
            const float sy = (nbi & 1) ? q.w : q.y;
            const float sm = (nbi & 1) ? mm.y : mm.x;
            const float dx = qx - sx;
            const float dy = qy - sy;
            const float sq = fmaf(dx, dx, dy * dy);
            const float r = __builtin_amdgcn_rsqf(sq);
            const float w = r * r * r * sm;
            ax = fmaf(dx, w, ax);
            ay = fmaf(dy, w, ay);
        }
    }

    // Wave butterfly reduction (fixed order).
    #pragma unroll
    for (int off = 32; off > 0; off >>= 1) {
        ax += __shfl_xor(ax, off);
        ay += __shfl_xor(ay, off);
    }

    if (lane == 0) red[wave] = make_float2(ax, ay);
    __syncthreads();

    // Combine the two halves (fixed order: h0 + h1) and write.
    if (h == 0 && lane == 0) {
        const float2 r0 = red[wave];
        const float2 r1 = red[wave + 1];
        const float sx = r0.x + r1.x;
        const float sy = r0.y + r1.y;
        const float m0inv = 1.0f / m[0];
        out[k] = make_float4(xk.z * m0inv, xk.w * m0inv, sx * m[k], sy * m[k]);
    }
}

extern "C" void kernel_launch(void* const* d_in, const int* in_sizes, int n_in,
                              void* d_out, int out_size, void* d_ws, size_t ws_size,
                              hipStream_t stream) {
    const float* x = (const float*)d_in[0];
    const float* m = (const float*)d_in[1];
    nbody_wave2<<<dim3(NBLK), dim3(TPB), 0, stream>>>(x, m, (float4*)d_out);
}